// Round 2
// baseline (2345.465 us; speedup 1.0000x reference)
//
#include <hip/hip_runtime.h>

// ======================================================================
// Involution net: 3 x (1x1 conv + dynamic-kernel apply w/ batch BN) + FC
// B=1024, fp32 (no fp32 MFMA on CDNA4 -> vector ALU).
//
// R2: p1 rewritten. acc tile 8x8 (64 VGPR) with split-row/split-col
// fragment layout: LDS fragment reads are lane-consecutive float4
// (conflict-free) or broadcast. Each thread owns 4 xi rows + 4 red rows
// -> uniform epilogue (xi store / shfl avgpool / BN-stat atomics).
// launch_bounds(...,4) pins 4 waves/SIMD.
// ======================================================================

static constexpr size_t OFF_WCAT1 = 0;
static constexpr size_t OFF_WCAT2 = 25600;
static constexpr size_t OFF_WCAT3 = 41984;
static constexpr size_t OFF_SUM1  = 107520;
static constexpr size_t OFF_SQS1  = 107584;
static constexpr size_t OFF_SUM2  = 107648;
static constexpr size_t OFF_SQS2  = 107776;
static constexpr size_t OFF_SUM3  = 107904;
static constexpr size_t OFF_SQS3  = 108160;
static constexpr size_t OFF_XI    = 108416;     // 16777216 floats
static constexpr size_t OFF_RPRE  = 16885632;   //  4194304
static constexpr size_t OFF_OUT1  = 21079936;   //  4194304
static constexpr size_t OFF_OUT2  = 25274240;   //  2097152
static constexpr size_t OFF_OUT3  = 27371392;   //  4194304

// ---------------- weight concat+transpose prep (one launch) ----------------
// wcatT[c][m] = m<cout ? W_init[m][c] : W_red[m-cout][c]
__global__ void prep_all(const float* __restrict__ wi1, const float* __restrict__ wr1,
                         const float* __restrict__ wi2, const float* __restrict__ wr2,
                         const float* __restrict__ wi3, const float* __restrict__ wr3,
                         float* __restrict__ w1, float* __restrict__ w2,
                         float* __restrict__ w3) {
    int e = blockIdx.x * 256 + threadIdx.x;
    const float* wi; const float* wr; float* wt; int cin, cout;
    if (e < 25600)      { wi = wi1; wr = wr1; wt = w1; cin = 200; cout = 64; }
    else if (e < 41984) { e -= 25600; wi = wi2; wr = wr2; wt = w2; cin = 64;  cout = 128; }
    else if (e < 107520){ e -= 41984; wi = wi3; wr = wr3; wt = w3; cin = 128; cout = 256; }
    else return;
    int M = 2 * cout, c = e / M, m = e % M;
    wt[e] = (m < cout) ? wi[m * cin + c] : wr[(m - cout) * cin + c];
}

// ---------------- P1 layer 1: CIN=200, COUT=64, 16x16, s=2 ----------------
// 512 thr: tn=tid%32 (cols tn*4 & 128+tn*4), tm=tid/32 (rows tm*4 & 64+tm*4)
__global__ __launch_bounds__(512, 4) void p1_l1(
    const float* __restrict__ x,     // [B][200][256]
    const float* __restrict__ wT,    // [200][128]
    float* __restrict__ xi,          // [B][64][256]
    float* __restrict__ rpre,        // [B][64][64]
    float* __restrict__ ssum, float* __restrict__ ssqs)
{
    constexpr int N = 256, M = 128, KC = 16;
    __shared__ float Xs[KC * N];
    __shared__ float Ws[KC * M];
    const int tid = threadIdx.x, tn = tid & 31, tm = tid >> 5, b = blockIdx.x;
    const float* xb = x + (size_t)b * 200 * N;

    float acc[8][8];
    #pragma unroll
    for (int i = 0; i < 8; ++i)
        #pragma unroll
        for (int j = 0; j < 8; ++j) acc[i][j] = 0.f;

    auto stage = [&](int c0, int kc) {
        for (int e = tid * 4; e < kc * N; e += 2048)
            *(float4*)(Xs + e) = *(const float4*)(xb + (size_t)c0 * N + e);
        for (int e = tid * 4; e < kc * M; e += 2048)
            *(float4*)(Ws + e) = *(const float4*)(wT + (size_t)c0 * M + e);
    };
    auto compute = [&](int c) {
        float4 xa = *(const float4*)(Xs + c * N + tn * 4);
        float4 xc = *(const float4*)(Xs + c * N + 128 + tn * 4);
        float4 wa = *(const float4*)(Ws + c * M + tm * 4);
        float4 wb = *(const float4*)(Ws + c * M + 64 + tm * 4);
        float xf[8] = {xa.x, xa.y, xa.z, xa.w, xc.x, xc.y, xc.z, xc.w};
        float wf[8] = {wa.x, wa.y, wa.z, wa.w, wb.x, wb.y, wb.z, wb.w};
        #pragma unroll
        for (int i = 0; i < 8; ++i)
            #pragma unroll
            for (int j = 0; j < 8; ++j)
                acc[i][j] = fmaf(wf[i], xf[j], acc[i][j]);
    };

    for (int c0 = 0; c0 + KC <= 200; c0 += KC) {
        stage(c0, KC); __syncthreads();
        #pragma unroll
        for (int c = 0; c < KC; ++c) compute(c);
        __syncthreads();
    }
    stage(192, 8); __syncthreads();
    #pragma unroll
    for (int c = 0; c < 8; ++c) compute(c);

    // epilogue: rows tm*4+i are xi, rows 64+tm*4+i are red
    const int gr = tm * 4;
    #pragma unroll
    for (int i = 0; i < 4; ++i) {
        float* dst = xi + ((size_t)b * 64 + gr + i) * N + tn * 4;
        float4 v0 = {acc[i][0], acc[i][1], acc[i][2], acc[i][3]};
        float4 v1 = {acc[i][4], acc[i][5], acc[i][6], acc[i][7]};
        *(float4*)dst = v0;
        *(float4*)(dst + 128) = v1;
    }
    const bool val = (tn & 4) == 0;   // h = tn/4 even
    #pragma unroll
    for (int i = 4; i < 8; ++i) {
        const int mr = gr + i - 4;
        float hp0 = acc[i][0] + acc[i][1], hp1 = acc[i][2] + acc[i][3];
        float hp2 = acc[i][4] + acc[i][5], hp3 = acc[i][6] + acc[i][7];
        float p0 = 0.25f * (hp0 + __shfl_xor(hp0, 4));
        float p1 = 0.25f * (hp1 + __shfl_xor(hp1, 4));
        float p2 = 0.25f * (hp2 + __shfl_xor(hp2, 4));
        float p3 = 0.25f * (hp3 + __shfl_xor(hp3, 4));
        float s1 = val ? (p0 + p1 + p2 + p3) : 0.f;
        float s2 = val ? (p0 * p0 + p1 * p1 + p2 * p2 + p3 * p3) : 0.f;
        if (val) {
            const int wo = (tn & 3) * 2, ho = tn >> 3;
            float* rp = rpre + ((size_t)b * 64 + mr) * 64;
            *(float2*)(rp + ho * 8 + wo) = float2{p0, p1};
            *(float2*)(rp + (4 + ho) * 8 + wo) = float2{p2, p3};
        }
        #pragma unroll
        for (int off = 1; off <= 16; off <<= 1) {
            s1 += __shfl_xor(s1, off); s2 += __shfl_xor(s2, off);
        }
        if (tn == 0) { atomicAdd(ssum + mr, s1); atomicAdd(ssqs + mr, s2); }
    }
}

// ---------------- P1 layer 2: CIN=64, COUT=128, 8x8, s=2 ----------------
// 256 thr: tn=tid%8 (cols tn*4 & 32+tn*4), tm=tid/8 (rows tm*4 & 128+tm*4)
__global__ __launch_bounds__(256, 4) void p1_l2(
    const float* __restrict__ x,     // [B][64][64]
    const float* __restrict__ wT,    // [64][256]
    float* __restrict__ xi,          // [B][128][64]
    float* __restrict__ rpre,        // [B][128][16]
    float* __restrict__ ssum, float* __restrict__ ssqs)
{
    constexpr int N = 64, M = 256, KC = 16;
    __shared__ float Xs[KC * N];
    __shared__ float Ws[KC * M];
    const int tid = threadIdx.x, tn = tid & 7, tm = tid >> 3, b = blockIdx.x;
    const float* xb = x + (size_t)b * 64 * N;

    float acc[8][8];
    #pragma unroll
    for (int i = 0; i < 8; ++i)
        #pragma unroll
        for (int j = 0; j < 8; ++j) acc[i][j] = 0.f;

    for (int c0 = 0; c0 < 64; c0 += KC) {
        for (int e = tid * 4; e < KC * N; e += 1024)
            *(float4*)(Xs + e) = *(const float4*)(xb + (size_t)c0 * N + e);
        for (int e = tid * 4; e < KC * M; e += 1024)
            *(float4*)(Ws + e) = *(const float4*)(wT + (size_t)c0 * M + e);
        __syncthreads();
        #pragma unroll
        for (int c = 0; c < KC; ++c) {
            float4 xa = *(const float4*)(Xs + c * N + tn * 4);
            float4 xc = *(const float4*)(Xs + c * N + 32 + tn * 4);
            float4 wa = *(const float4*)(Ws + c * M + tm * 4);
            float4 wb = *(const float4*)(Ws + c * M + 128 + tm * 4);
            float xf[8] = {xa.x, xa.y, xa.z, xa.w, xc.x, xc.y, xc.z, xc.w};
            float wf[8] = {wa.x, wa.y, wa.z, wa.w, wb.x, wb.y, wb.z, wb.w};
            #pragma unroll
            for (int i = 0; i < 8; ++i)
                #pragma unroll
                for (int j = 0; j < 8; ++j)
                    acc[i][j] = fmaf(wf[i], xf[j], acc[i][j]);
        }
        __syncthreads();
    }

    const int gr = tm * 4;
    #pragma unroll
    for (int i = 0; i < 4; ++i) {
        float* dst = xi + ((size_t)b * 128 + gr + i) * N + tn * 4;
        float4 v0 = {acc[i][0], acc[i][1], acc[i][2], acc[i][3]};
        float4 v1 = {acc[i][4], acc[i][5], acc[i][6], acc[i][7]};
        *(float4*)dst = v0;
        *(float4*)(dst + 32) = v1;
    }
    const bool val = (tn & 2) == 0;   // h = tn/2 even
    #pragma unroll
    for (int i = 4; i < 8; ++i) {
        const int mr = gr + i - 4;
        float hp0 = acc[i][0] + acc[i][1], hp1 = acc[i][2] + acc[i][3];
        float hp2 = acc[i][4] + acc[i][5], hp3 = acc[i][6] + acc[i][7];
        float p0 = 0.25f * (hp0 + __shfl_xor(hp0, 2));
        float p1 = 0.25f * (hp1 + __shfl_xor(hp1, 2));
        float p2 = 0.25f * (hp2 + __shfl_xor(hp2, 2));
        float p3 = 0.25f * (hp3 + __shfl_xor(hp3, 2));
        float s1 = val ? (p0 + p1 + p2 + p3) : 0.f;
        float s2 = val ? (p0 * p0 + p1 * p1 + p2 * p2 + p3 * p3) : 0.f;
        if (val) {
            const int wo = (tn & 1) * 2, ho = tn >> 2;
            float* rp = rpre + ((size_t)b * 128 + mr) * 16;
            *(float2*)(rp + ho * 4 + wo) = float2{p0, p1};
            *(float2*)(rp + (2 + ho) * 4 + wo) = float2{p2, p3};
        }
        #pragma unroll
        for (int off = 1; off <= 4; off <<= 1) {
            s1 += __shfl_xor(s1, off); s2 += __shfl_xor(s2, off);
        }
        if (tn == 0) { atomicAdd(ssum + mr, s1); atomicAdd(ssqs + mr, s2); }
    }
}

// ---------------- P1 layer 3: CIN=128, COUT=256, 4x4, s=1 ----------------
// 256 thr: tn=tid%4 (cols tn*4), tm=tid/4 (rows tm*4 & 256+tm*4)
__global__ __launch_bounds__(256, 4) void p1_l3(
    const float* __restrict__ x,     // [B][128][16]
    const float* __restrict__ wT,    // [128][512]
    float* __restrict__ xi,          // [B][256][16]
    float* __restrict__ rpre,        // [B][256][16]
    float* __restrict__ ssum, float* __restrict__ ssqs)
{
    constexpr int N = 16, M = 512, KC = 16;
    __shared__ float Xs[KC * N];
    __shared__ float Ws[KC * M];
    const int tid = threadIdx.x, tn = tid & 3, tm = tid >> 2, b = blockIdx.x;
    const float* xb = x + (size_t)b * 128 * N;

    float acc[8][4];
    #pragma unroll
    for (int i = 0; i < 8; ++i)
        #pragma unroll
        for (int j = 0; j < 4; ++j) acc[i][j] = 0.f;

    for (int c0 = 0; c0 < 128; c0 += KC) {
        for (int e = tid * 4; e < KC * N; e += 1024)
            *(float4*)(Xs + e) = *(const float4*)(xb + (size_t)c0 * N + e);
        for (int e = tid * 4; e < KC * M; e += 1024)
            *(float4*)(Ws + e) = *(const float4*)(wT + (size_t)c0 * M + e);
        __syncthreads();
        #pragma unroll
        for (int c = 0; c < KC; ++c) {
            float4 xa = *(const float4*)(Xs + c * N + tn * 4);
            float4 wa = *(const float4*)(Ws + c * M + tm * 4);
            float4 wb = *(const float4*)(Ws + c * M + 256 + tm * 4);
            float xf[4] = {xa.x, xa.y, xa.z, xa.w};
            float wf[8] = {wa.x, wa.y, wa.z, wa.w, wb.x, wb.y, wb.z, wb.w};
            #pragma unroll
            for (int i = 0; i < 8; ++i)
                #pragma unroll
                for (int j = 0; j < 4; ++j)
                    acc[i][j] = fmaf(wf[i], xf[j], acc[i][j]);
        }
        __syncthreads();
    }

    const int gr = tm * 4;
    #pragma unroll
    for (int i = 0; i < 4; ++i) {
        float4 v0 = {acc[i][0], acc[i][1], acc[i][2], acc[i][3]};
        *(float4*)(xi + ((size_t)b * 256 + gr + i) * 16 + tn * 4) = v0;
    }
    #pragma unroll
    for (int i = 4; i < 8; ++i) {
        const int mr = gr + i - 4;
        float4 v0 = {acc[i][0], acc[i][1], acc[i][2], acc[i][3]};
        *(float4*)(rpre + ((size_t)b * 256 + mr) * 16 + tn * 4) = v0;
        float s1 = acc[i][0] + acc[i][1] + acc[i][2] + acc[i][3];
        float s2 = acc[i][0] * acc[i][0] + acc[i][1] * acc[i][1]
                 + acc[i][2] * acc[i][2] + acc[i][3] * acc[i][3];
        s1 += __shfl_xor(s1, 1); s2 += __shfl_xor(s2, 1);
        s1 += __shfl_xor(s1, 2); s2 += __shfl_xor(s2, 2);
        if (tn == 0) { atomicAdd(ssum + mr, s1); atomicAdd(ssqs + mr, s2); }
    }
}

// ---------------- P3 ----------------
template<int COUT, int H, int W, int K, int S, int PAD>
__global__ __launch_bounds__(256) void p3_kernel(
    const float* __restrict__ xi,    // [B][COUT][H*W]
    const float* __restrict__ rpre,  // [B][COUT][NQ]
    const float* __restrict__ ssum,
    const float* __restrict__ ssqs,
    const float* __restrict__ gamma,
    const float* __restrict__ beta,
    const float* __restrict__ wspan, // [K*K][COUT]
    float* __restrict__ out,         // [B][COUT][NQ]
    float inv_cnt)
{
    constexpr int HO = (S == 2) ? H / 2 : H;
    constexpr int WO = (S == 2) ? W / 2 : W;
    constexpr int NQ = HO * WO;
    constexpr int K2 = K * K;
    constexpr int N  = H * W;
    static_assert((S == 2 && K == 2 && PAD == 0) || (S == 1 && K == 3 && PAD == 1), "");

    __shared__ float sc[COUT], sh[COUT];
    __shared__ float rl[COUT * NQ];
    __shared__ float kl[K2 * NQ];
    __shared__ float xil[(S == 1) ? COUT * N : 4];

    const int tid = threadIdx.x;
    const int b   = blockIdx.x;

    for (int o = tid; o < COUT; o += 256) {
        float mean = ssum[o] * inv_cnt;
        float var  = ssqs[o] * inv_cnt - mean * mean;
        float s    = gamma[o] * rsqrtf(var + 1e-5f);
        sc[o] = s;
        sh[o] = beta[o] - mean * s;
    }
    __syncthreads();

    const float* rp = rpre + (size_t)b * COUT * NQ;
    for (int e = tid; e < COUT * NQ; e += 256) {
        int o = e / NQ;
        rl[e] = fmaxf(fmaf(sc[o], rp[e], sh[o]), 0.f);
    }
    const float* xb = xi + (size_t)b * COUT * N;
    if (S == 1) {
        for (int e = tid; e < COUT * N / 4; e += 256)
            ((float4*)xil)[e] = ((const float4*)xb)[e];
    }
    __syncthreads();

    for (int e = tid; e < K2 * NQ; e += 256) {
        int kk = e / NQ, q = e % NQ;
        float s = 0.f;
        for (int o = 0; o < COUT; ++o)
            s = fmaf(wspan[kk * COUT + o], rl[o * NQ + q], s);
        kl[e] = s;
    }
    __syncthreads();

    float* ob = out + (size_t)b * COUT * NQ;
    for (int e = tid; e < COUT * NQ; e += 256) {
        int o = e / NQ, q = e % NQ, ho = q / WO, wo = q % WO;
        float v;
        if (S == 2) {
            const float* p = xb + ((size_t)o * H + 2 * ho) * W + 2 * wo;
            float2 t  = *(const float2*)p;
            float2 bo = *(const float2*)(p + W);
            v = kl[0 * NQ + q] * t.x + kl[1 * NQ + q] * t.y
              + kl[2 * NQ + q] * bo.x + kl[3 * NQ + q] * bo.y;
        } else {
            v = 0.f;
            const float* xo = xil + o * N;
            #pragma unroll
            for (int ki = 0; ki < 3; ++ki) {
                int h = ho + ki - 1;
                if (h < 0 || h >= H) continue;
                #pragma unroll
                for (int kj = 0; kj < 3; ++kj) {
                    int w = wo + kj - 1;
                    if (w < 0 || w >= W) continue;
                    v = fmaf(kl[(ki * 3 + kj) * NQ + q], xo[h * W + w], v);
                }
            }
        }
        ob[e] = v;
    }
}

// ---------------- FC ----------------
__global__ __launch_bounds__(256) void fc_kernel(
    const float* __restrict__ h,    // [B][4096]
    const float* __restrict__ wfc,  // [16][4096]
    const float* __restrict__ bfc,  // [16]
    float* __restrict__ out)        // [B][16]
{
    __shared__ float hl[4096];
    __shared__ float red[4][16];
    const int tid = threadIdx.x, b = blockIdx.x;
    const float* hb = h + (size_t)b * 4096;
    for (int e = tid; e < 1024; e += 256)
        ((float4*)hl)[e] = ((const float4*)hb)[e];
    __syncthreads();
    float acc[16];
    #pragma unroll
    for (int n = 0; n < 16; ++n) acc[n] = 0.f;
    for (int i = 0; i < 16; ++i) {
        int f = tid + i * 256;
        float hv = hl[f];
        #pragma unroll
        for (int n = 0; n < 16; ++n)
            acc[n] = fmaf(hv, wfc[n * 4096 + f], acc[n]);
    }
    #pragma unroll
    for (int n = 0; n < 16; ++n) {
        float v = acc[n];
        #pragma unroll
        for (int off = 1; off < 64; off <<= 1) v += __shfl_xor(v, off);
        acc[n] = v;
    }
    const int wave = tid >> 6, lane = tid & 63;
    if (lane == 0) {
        #pragma unroll
        for (int n = 0; n < 16; ++n) red[wave][n] = acc[n];
    }
    __syncthreads();
    if (tid < 16)
        out[(size_t)b * 16 + tid] =
            red[0][tid] + red[1][tid] + red[2][tid] + red[3][tid] + bfc[tid];
}

// ---------------- launch ----------------
extern "C" void kernel_launch(void* const* d_in, const int* in_sizes, int n_in,
                              void* d_out, int out_size, void* d_ws, size_t ws_size,
                              hipStream_t stream) {
    const float* x    = (const float*)d_in[0];
    const float* Wi1  = (const float*)d_in[1];
    const float* Wr1  = (const float*)d_in[2];
    const float* g1   = (const float*)d_in[3];
    const float* be1  = (const float*)d_in[4];
    const float* Wsp1 = (const float*)d_in[5];
    const float* Wi2  = (const float*)d_in[6];
    const float* Wr2  = (const float*)d_in[7];
    const float* g2   = (const float*)d_in[8];
    const float* be2  = (const float*)d_in[9];
    const float* Wsp2 = (const float*)d_in[10];
    const float* Wi3  = (const float*)d_in[11];
    const float* Wr3  = (const float*)d_in[12];
    const float* g3   = (const float*)d_in[13];
    const float* be3  = (const float*)d_in[14];
    const float* Wsp3 = (const float*)d_in[15];
    const float* Wfc  = (const float*)d_in[16];
    const float* bfc  = (const float*)d_in[17];
    float* out = (float*)d_out;
    float* ws  = (float*)d_ws;

    float* wcat1 = ws + OFF_WCAT1;
    float* wcat2 = ws + OFF_WCAT2;
    float* wcat3 = ws + OFF_WCAT3;
    float* sum1 = ws + OFF_SUM1; float* sqs1 = ws + OFF_SQS1;
    float* sum2 = ws + OFF_SUM2; float* sqs2 = ws + OFF_SQS2;
    float* sum3 = ws + OFF_SUM3; float* sqs3 = ws + OFF_SQS3;
    float* xiA  = ws + OFF_XI;
    float* rB   = ws + OFF_RPRE;
    float* out1 = ws + OFF_OUT1;
    float* out2 = ws + OFF_OUT2;
    float* out3 = ws + OFF_OUT3;

    hipMemsetAsync(sum1, 0, 896 * sizeof(float), stream);

    prep_all<<<420, 256, 0, stream>>>(Wi1, Wr1, Wi2, Wr2, Wi3, Wr3, wcat1, wcat2, wcat3);

    p1_l1<<<1024, 512, 0, stream>>>(x, wcat1, xiA, rB, sum1, sqs1);
    p3_kernel<64, 16, 16, 2, 2, 0><<<1024, 256, 0, stream>>>(
        xiA, rB, sum1, sqs1, g1, be1, Wsp1, out1, 1.f / (1024.f * 64.f));

    p1_l2<<<1024, 256, 0, stream>>>(out1, wcat2, xiA, rB, sum2, sqs2);
    p3_kernel<128, 8, 8, 2, 2, 0><<<1024, 256, 0, stream>>>(
        xiA, rB, sum2, sqs2, g2, be2, Wsp2, out2, 1.f / (1024.f * 16.f));

    p1_l3<<<1024, 256, 0, stream>>>(out2, wcat3, xiA, rB, sum3, sqs3);
    p3_kernel<256, 4, 4, 3, 1, 1><<<1024, 256, 0, stream>>>(
        xiA, rB, sum3, sqs3, g3, be3, Wsp3, out3, 1.f / (1024.f * 16.f));

    fc_kernel<<<1024, 256, 0, stream>>>(out3, Wfc, bfc, out);
}

// Round 3
// 894.439 us; speedup vs baseline: 2.6223x; 2.6223x over previous
//
#include <hip/hip_runtime.h>

// ======================================================================
// Involution net: 3 x (1x1 conv + dynamic-kernel apply w/ batch BN) + FC
// B=1024, fp32 (no fp32 MFMA on CDNA4 -> vector ALU).
//
// R3: R2's conflict-free split-fragment p1 kernels, but WITHOUT the
// min-waves launch_bounds arg. R2's (512,4)/(256,4) capped the allocator
// at 64 regs -> acc[8][8] spilled to scratch (6.5 GB HBM traffic/dispatch,
// VALUBusy 7.5%). Plain (512)/(256) lets acc live in VGPR+AGPR (R1
// evidence: 84 VGPR, zero spill). Stats zeroing folded into prep_all.
// ======================================================================

static constexpr size_t OFF_WCAT1 = 0;
static constexpr size_t OFF_WCAT2 = 25600;
static constexpr size_t OFF_WCAT3 = 41984;
static constexpr size_t OFF_SUM1  = 107520;   // 896 stat floats start here
static constexpr size_t OFF_SQS1  = 107584;
static constexpr size_t OFF_SUM2  = 107648;
static constexpr size_t OFF_SQS2  = 107776;
static constexpr size_t OFF_SUM3  = 107904;
static constexpr size_t OFF_SQS3  = 108160;
static constexpr size_t OFF_XI    = 108416;     // 16777216 floats
static constexpr size_t OFF_RPRE  = 16885632;   //  4194304
static constexpr size_t OFF_OUT1  = 21079936;   //  4194304
static constexpr size_t OFF_OUT2  = 25274240;   //  2097152
static constexpr size_t OFF_OUT3  = 27371392;   //  4194304

// ---------------- weight concat+transpose prep + stat zero ----------------
// wcatT[c][m] = m<cout ? W_init[m][c] : W_red[m-cout][c]
__global__ void prep_all(const float* __restrict__ wi1, const float* __restrict__ wr1,
                         const float* __restrict__ wi2, const float* __restrict__ wr2,
                         const float* __restrict__ wi3, const float* __restrict__ wr3,
                         float* __restrict__ ws) {
    int e = blockIdx.x * 256 + threadIdx.x;
    if (e >= 108416) return;
    if (e >= 107520) { ws[e] = 0.f; return; }     // BN stat accumulators
    const float* wi; const float* wr; float* wt; int cin, cout;
    if (e < 25600)      { wi = wi1; wr = wr1; wt = ws + OFF_WCAT1; cin = 200; cout = 64; }
    else if (e < 41984) { e -= 25600; wi = wi2; wr = wr2; wt = ws + OFF_WCAT2; cin = 64;  cout = 128; }
    else                { e -= 41984; wi = wi3; wr = wr3; wt = ws + OFF_WCAT3; cin = 128; cout = 256; }
    int M = 2 * cout, c = e / M, m = e % M;
    wt[e] = (m < cout) ? wi[m * cin + c] : wr[(m - cout) * cin + c];
}

// ---------------- P1 layer 1: CIN=200, COUT=64, 16x16, s=2 ----------------
// 512 thr: tn=tid%32 (cols tn*4 & 128+tn*4), tm=tid/32 (rows tm*4 & 64+tm*4)
__global__ __launch_bounds__(512) void p1_l1(
    const float* __restrict__ x,     // [B][200][256]
    const float* __restrict__ wT,    // [200][128]
    float* __restrict__ xi,          // [B][64][256]
    float* __restrict__ rpre,        // [B][64][64]
    float* __restrict__ ssum, float* __restrict__ ssqs)
{
    constexpr int N = 256, M = 128, KC = 16;
    __shared__ float Xs[KC * N];
    __shared__ float Ws[KC * M];
    const int tid = threadIdx.x, tn = tid & 31, tm = tid >> 5, b = blockIdx.x;
    const float* xb = x + (size_t)b * 200 * N;

    float acc[8][8];
    #pragma unroll
    for (int i = 0; i < 8; ++i)
        #pragma unroll
        for (int j = 0; j < 8; ++j) acc[i][j] = 0.f;

    auto stage = [&](int c0, int kc) {
        for (int e = tid * 4; e < kc * N; e += 2048)
            *(float4*)(Xs + e) = *(const float4*)(xb + (size_t)c0 * N + e);
        for (int e = tid * 4; e < kc * M; e += 2048)
            *(float4*)(Ws + e) = *(const float4*)(wT + (size_t)c0 * M + e);
    };
    auto compute = [&](int c) {
        float4 xa = *(const float4*)(Xs + c * N + tn * 4);
        float4 xc = *(const float4*)(Xs + c * N + 128 + tn * 4);
        float4 wa = *(const float4*)(Ws + c * M + tm * 4);
        float4 wb = *(const float4*)(Ws + c * M + 64 + tm * 4);
        float xf[8] = {xa.x, xa.y, xa.z, xa.w, xc.x, xc.y, xc.z, xc.w};
        float wf[8] = {wa.x, wa.y, wa.z, wa.w, wb.x, wb.y, wb.z, wb.w};
        #pragma unroll
        for (int i = 0; i < 8; ++i)
            #pragma unroll
            for (int j = 0; j < 8; ++j)
                acc[i][j] = fmaf(wf[i], xf[j], acc[i][j]);
    };

    for (int c0 = 0; c0 + KC <= 200; c0 += KC) {
        stage(c0, KC); __syncthreads();
        #pragma unroll
        for (int c = 0; c < KC; ++c) compute(c);
        __syncthreads();
    }
    stage(192, 8); __syncthreads();
    #pragma unroll
    for (int c = 0; c < 8; ++c) compute(c);

    // epilogue: rows tm*4+i are xi, rows 64+tm*4+i are red
    const int gr = tm * 4;
    #pragma unroll
    for (int i = 0; i < 4; ++i) {
        float* dst = xi + ((size_t)b * 64 + gr + i) * N + tn * 4;
        float4 v0 = {acc[i][0], acc[i][1], acc[i][2], acc[i][3]};
        float4 v1 = {acc[i][4], acc[i][5], acc[i][6], acc[i][7]};
        *(float4*)dst = v0;
        *(float4*)(dst + 128) = v1;
    }
    const bool val = (tn & 4) == 0;   // h = tn/4 even
    #pragma unroll
    for (int i = 4; i < 8; ++i) {
        const int mr = gr + i - 4;
        float hp0 = acc[i][0] + acc[i][1], hp1 = acc[i][2] + acc[i][3];
        float hp2 = acc[i][4] + acc[i][5], hp3 = acc[i][6] + acc[i][7];
        float p0 = 0.25f * (hp0 + __shfl_xor(hp0, 4));
        float p1 = 0.25f * (hp1 + __shfl_xor(hp1, 4));
        float p2 = 0.25f * (hp2 + __shfl_xor(hp2, 4));
        float p3 = 0.25f * (hp3 + __shfl_xor(hp3, 4));
        float s1 = val ? (p0 + p1 + p2 + p3) : 0.f;
        float s2 = val ? (p0 * p0 + p1 * p1 + p2 * p2 + p3 * p3) : 0.f;
        if (val) {
            const int wo = (tn & 3) * 2, ho = tn >> 3;
            float* rp = rpre + ((size_t)b * 64 + mr) * 64;
            *(float2*)(rp + ho * 8 + wo) = float2{p0, p1};
            *(float2*)(rp + (4 + ho) * 8 + wo) = float2{p2, p3};
        }
        #pragma unroll
        for (int off = 1; off <= 16; off <<= 1) {
            s1 += __shfl_xor(s1, off); s2 += __shfl_xor(s2, off);
        }
        if (tn == 0) { atomicAdd(ssum + mr, s1); atomicAdd(ssqs + mr, s2); }
    }
}

// ---------------- P1 layer 2: CIN=64, COUT=128, 8x8, s=2 ----------------
// 256 thr: tn=tid%8 (cols tn*4 & 32+tn*4), tm=tid/8 (rows tm*4 & 128+tm*4)
__global__ __launch_bounds__(256) void p1_l2(
    const float* __restrict__ x,     // [B][64][64]
    const float* __restrict__ wT,    // [64][256]
    float* __restrict__ xi,          // [B][128][64]
    float* __restrict__ rpre,        // [B][128][16]
    float* __restrict__ ssum, float* __restrict__ ssqs)
{
    constexpr int N = 64, M = 256, KC = 16;
    __shared__ float Xs[KC * N];
    __shared__ float Ws[KC * M];
    const int tid = threadIdx.x, tn = tid & 7, tm = tid >> 3, b = blockIdx.x;
    const float* xb = x + (size_t)b * 64 * N;

    float acc[8][8];
    #pragma unroll
    for (int i = 0; i < 8; ++i)
        #pragma unroll
        for (int j = 0; j < 8; ++j) acc[i][j] = 0.f;

    for (int c0 = 0; c0 < 64; c0 += KC) {
        for (int e = tid * 4; e < KC * N; e += 1024)
            *(float4*)(Xs + e) = *(const float4*)(xb + (size_t)c0 * N + e);
        for (int e = tid * 4; e < KC * M; e += 1024)
            *(float4*)(Ws + e) = *(const float4*)(wT + (size_t)c0 * M + e);
        __syncthreads();
        #pragma unroll
        for (int c = 0; c < KC; ++c) {
            float4 xa = *(const float4*)(Xs + c * N + tn * 4);
            float4 xc = *(const float4*)(Xs + c * N + 32 + tn * 4);
            float4 wa = *(const float4*)(Ws + c * M + tm * 4);
            float4 wb = *(const float4*)(Ws + c * M + 128 + tm * 4);
            float xf[8] = {xa.x, xa.y, xa.z, xa.w, xc.x, xc.y, xc.z, xc.w};
            float wf[8] = {wa.x, wa.y, wa.z, wa.w, wb.x, wb.y, wb.z, wb.w};
            #pragma unroll
            for (int i = 0; i < 8; ++i)
                #pragma unroll
                for (int j = 0; j < 8; ++j)
                    acc[i][j] = fmaf(wf[i], xf[j], acc[i][j]);
        }
        __syncthreads();
    }

    const int gr = tm * 4;
    #pragma unroll
    for (int i = 0; i < 4; ++i) {
        float* dst = xi + ((size_t)b * 128 + gr + i) * N + tn * 4;
        float4 v0 = {acc[i][0], acc[i][1], acc[i][2], acc[i][3]};
        float4 v1 = {acc[i][4], acc[i][5], acc[i][6], acc[i][7]};
        *(float4*)dst = v0;
        *(float4*)(dst + 32) = v1;
    }
    const bool val = (tn & 2) == 0;   // h = tn/2 even
    #pragma unroll
    for (int i = 4; i < 8; ++i) {
        const int mr = gr + i - 4;
        float hp0 = acc[i][0] + acc[i][1], hp1 = acc[i][2] + acc[i][3];
        float hp2 = acc[i][4] + acc[i][5], hp3 = acc[i][6] + acc[i][7];
        float p0 = 0.25f * (hp0 + __shfl_xor(hp0, 2));
        float p1 = 0.25f * (hp1 + __shfl_xor(hp1, 2));
        float p2 = 0.25f * (hp2 + __shfl_xor(hp2, 2));
        float p3 = 0.25f * (hp3 + __shfl_xor(hp3, 2));
        float s1 = val ? (p0 + p1 + p2 + p3) : 0.f;
        float s2 = val ? (p0 * p0 + p1 * p1 + p2 * p2 + p3 * p3) : 0.f;
        if (val) {
            const int wo = (tn & 1) * 2, ho = tn >> 2;
            float* rp = rpre + ((size_t)b * 128 + mr) * 16;
            *(float2*)(rp + ho * 4 + wo) = float2{p0, p1};
            *(float2*)(rp + (2 + ho) * 4 + wo) = float2{p2, p3};
        }
        #pragma unroll
        for (int off = 1; off <= 4; off <<= 1) {
            s1 += __shfl_xor(s1, off); s2 += __shfl_xor(s2, off);
        }
        if (tn == 0) { atomicAdd(ssum + mr, s1); atomicAdd(ssqs + mr, s2); }
    }
}

// ---------------- P1 layer 3: CIN=128, COUT=256, 4x4, s=1 ----------------
// 256 thr: tn=tid%4 (cols tn*4), tm=tid/4 (rows tm*4 & 256+tm*4)
__global__ __launch_bounds__(256) void p1_l3(
    const float* __restrict__ x,     // [B][128][16]
    const float* __restrict__ wT,    // [128][512]
    float* __restrict__ xi,          // [B][256][16]
    float* __restrict__ rpre,        // [B][256][16]
    float* __restrict__ ssum, float* __restrict__ ssqs)
{
    constexpr int N = 16, M = 512, KC = 16;
    __shared__ float Xs[KC * N];
    __shared__ float Ws[KC * M];
    const int tid = threadIdx.x, tn = tid & 3, tm = tid >> 2, b = blockIdx.x;
    const float* xb = x + (size_t)b * 128 * N;

    float acc[8][4];
    #pragma unroll
    for (int i = 0; i < 8; ++i)
        #pragma unroll
        for (int j = 0; j < 4; ++j) acc[i][j] = 0.f;

    for (int c0 = 0; c0 < 128; c0 += KC) {
        for (int e = tid * 4; e < KC * N; e += 1024)
            *(float4*)(Xs + e) = *(const float4*)(xb + (size_t)c0 * N + e);
        for (int e = tid * 4; e < KC * M; e += 1024)
            *(float4*)(Ws + e) = *(const float4*)(wT + (size_t)c0 * M + e);
        __syncthreads();
        #pragma unroll
        for (int c = 0; c < KC; ++c) {
            float4 xa = *(const float4*)(Xs + c * N + tn * 4);
            float4 wa = *(const float4*)(Ws + c * M + tm * 4);
            float4 wb = *(const float4*)(Ws + c * M + 256 + tm * 4);
            float xf[4] = {xa.x, xa.y, xa.z, xa.w};
            float wf[8] = {wa.x, wa.y, wa.z, wa.w, wb.x, wb.y, wb.z, wb.w};
            #pragma unroll
            for (int i = 0; i < 8; ++i)
                #pragma unroll
                for (int j = 0; j < 4; ++j)
                    acc[i][j] = fmaf(wf[i], xf[j], acc[i][j]);
        }
        __syncthreads();
    }

    const int gr = tm * 4;
    #pragma unroll
    for (int i = 0; i < 4; ++i) {
        float4 v0 = {acc[i][0], acc[i][1], acc[i][2], acc[i][3]};
        *(float4*)(xi + ((size_t)b * 256 + gr + i) * 16 + tn * 4) = v0;
    }
    #pragma unroll
    for (int i = 4; i < 8; ++i) {
        const int mr = gr + i - 4;
        float4 v0 = {acc[i][0], acc[i][1], acc[i][2], acc[i][3]};
        *(float4*)(rpre + ((size_t)b * 256 + mr) * 16 + tn * 4) = v0;
        float s1 = acc[i][0] + acc[i][1] + acc[i][2] + acc[i][3];
        float s2 = acc[i][0] * acc[i][0] + acc[i][1] * acc[i][1]
                 + acc[i][2] * acc[i][2] + acc[i][3] * acc[i][3];
        s1 += __shfl_xor(s1, 1); s2 += __shfl_xor(s2, 1);
        s1 += __shfl_xor(s1, 2); s2 += __shfl_xor(s2, 2);
        if (tn == 0) { atomicAdd(ssum + mr, s1); atomicAdd(ssqs + mr, s2); }
    }
}

// ---------------- P3 ----------------
template<int COUT, int H, int W, int K, int S, int PAD>
__global__ __launch_bounds__(256) void p3_kernel(
    const float* __restrict__ xi,    // [B][COUT][H*W]
    const float* __restrict__ rpre,  // [B][COUT][NQ]
    const float* __restrict__ ssum,
    const float* __restrict__ ssqs,
    const float* __restrict__ gamma,
    const float* __restrict__ beta,
    const float* __restrict__ wspan, // [K*K][COUT]
    float* __restrict__ out,         // [B][COUT][NQ]
    float inv_cnt)
{
    constexpr int HO = (S == 2) ? H / 2 : H;
    constexpr int WO = (S == 2) ? W / 2 : W;
    constexpr int NQ = HO * WO;
    constexpr int K2 = K * K;
    constexpr int N  = H * W;
    static_assert((S == 2 && K == 2 && PAD == 0) || (S == 1 && K == 3 && PAD == 1), "");

    __shared__ float sc[COUT], sh[COUT];
    __shared__ float rl[COUT * NQ];
    __shared__ float kl[K2 * NQ];
    __shared__ float xil[(S == 1) ? COUT * N : 4];

    const int tid = threadIdx.x;
    const int b   = blockIdx.x;

    for (int o = tid; o < COUT; o += 256) {
        float mean = ssum[o] * inv_cnt;
        float var  = ssqs[o] * inv_cnt - mean * mean;
        float s    = gamma[o] * rsqrtf(var + 1e-5f);
        sc[o] = s;
        sh[o] = beta[o] - mean * s;
    }
    __syncthreads();

    const float* rp = rpre + (size_t)b * COUT * NQ;
    for (int e = tid; e < COUT * NQ; e += 256) {
        int o = e / NQ;
        rl[e] = fmaxf(fmaf(sc[o], rp[e], sh[o]), 0.f);
    }
    const float* xb = xi + (size_t)b * COUT * N;
    if (S == 1) {
        for (int e = tid; e < COUT * N / 4; e += 256)
            ((float4*)xil)[e] = ((const float4*)xb)[e];
    }
    __syncthreads();

    for (int e = tid; e < K2 * NQ; e += 256) {
        int kk = e / NQ, q = e % NQ;
        float s = 0.f;
        for (int o = 0; o < COUT; ++o)
            s = fmaf(wspan[kk * COUT + o], rl[o * NQ + q], s);
        kl[e] = s;
    }
    __syncthreads();

    float* ob = out + (size_t)b * COUT * NQ;
    for (int e = tid; e < COUT * NQ; e += 256) {
        int o = e / NQ, q = e % NQ, ho = q / WO, wo = q % WO;
        float v;
        if (S == 2) {
            const float* p = xb + ((size_t)o * H + 2 * ho) * W + 2 * wo;
            float2 t  = *(const float2*)p;
            float2 bo = *(const float2*)(p + W);
            v = kl[0 * NQ + q] * t.x + kl[1 * NQ + q] * t.y
              + kl[2 * NQ + q] * bo.x + kl[3 * NQ + q] * bo.y;
        } else {
            v = 0.f;
            const float* xo = xil + o * N;
            #pragma unroll
            for (int ki = 0; ki < 3; ++ki) {
                int h = ho + ki - 1;
                if (h < 0 || h >= H) continue;
                #pragma unroll
                for (int kj = 0; kj < 3; ++kj) {
                    int w = wo + kj - 1;
                    if (w < 0 || w >= W) continue;
                    v = fmaf(kl[(ki * 3 + kj) * NQ + q], xo[h * W + w], v);
                }
            }
        }
        ob[e] = v;
    }
}

// ---------------- FC ----------------
__global__ __launch_bounds__(256) void fc_kernel(
    const float* __restrict__ h,    // [B][4096]
    const float* __restrict__ wfc,  // [16][4096]
    const float* __restrict__ bfc,  // [16]
    float* __restrict__ out)        // [B][16]
{
    __shared__ float hl[4096];
    __shared__ float red[4][16];
    const int tid = threadIdx.x, b = blockIdx.x;
    const float* hb = h + (size_t)b * 4096;
    for (int e = tid; e < 1024; e += 256)
        ((float4*)hl)[e] = ((const float4*)hb)[e];
    __syncthreads();
    float acc[16];
    #pragma unroll
    for (int n = 0; n < 16; ++n) acc[n] = 0.f;
    for (int i = 0; i < 16; ++i) {
        int f = tid + i * 256;
        float hv = hl[f];
        #pragma unroll
        for (int n = 0; n < 16; ++n)
            acc[n] = fmaf(hv, wfc[n * 4096 + f], acc[n]);
    }
    #pragma unroll
    for (int n = 0; n < 16; ++n) {
        float v = acc[n];
        #pragma unroll
        for (int off = 1; off < 64; off <<= 1) v += __shfl_xor(v, off);
        acc[n] = v;
    }
    const int wave = tid >> 6, lane = tid & 63;
    if (lane == 0) {
        #pragma unroll
        for (int n = 0; n < 16; ++n) red[wave][n] = acc[n];
    }
    __syncthreads();
    if (tid < 16)
        out[(size_t)b * 16 + tid] =
            red[0][tid] + red[1][tid] + red[2][tid] + red[3][tid] + bfc[tid];
}

// ---------------- launch ----------------
extern "C" void kernel_launch(void* const* d_in, const int* in_sizes, int n_in,
                              void* d_out, int out_size, void* d_ws, size_t ws_size,
                              hipStream_t stream) {
    const float* x    = (const float*)d_in[0];
    const float* Wi1  = (const float*)d_in[1];
    const float* Wr1  = (const float*)d_in[2];
    const float* g1   = (const float*)d_in[3];
    const float* be1  = (const float*)d_in[4];
    const float* Wsp1 = (const float*)d_in[5];
    const float* Wi2  = (const float*)d_in[6];
    const float* Wr2  = (const float*)d_in[7];
    const float* g2   = (const float*)d_in[8];
    const float* be2  = (const float*)d_in[9];
    const float* Wsp2 = (const float*)d_in[10];
    const float* Wi3  = (const float*)d_in[11];
    const float* Wr3  = (const float*)d_in[12];
    const float* g3   = (const float*)d_in[13];
    const float* be3  = (const float*)d_in[14];
    const float* Wsp3 = (const float*)d_in[15];
    const float* Wfc  = (const float*)d_in[16];
    const float* bfc  = (const float*)d_in[17];
    float* out = (float*)d_out;
    float* ws  = (float*)d_ws;

    float* wcat1 = ws + OFF_WCAT1;
    float* wcat2 = ws + OFF_WCAT2;
    float* wcat3 = ws + OFF_WCAT3;
    float* sum1 = ws + OFF_SUM1; float* sqs1 = ws + OFF_SQS1;
    float* sum2 = ws + OFF_SUM2; float* sqs2 = ws + OFF_SQS2;
    float* sum3 = ws + OFF_SUM3; float* sqs3 = ws + OFF_SQS3;
    float* xiA  = ws + OFF_XI;
    float* rB   = ws + OFF_RPRE;
    float* out1 = ws + OFF_OUT1;
    float* out2 = ws + OFF_OUT2;
    float* out3 = ws + OFF_OUT3;

    prep_all<<<424, 256, 0, stream>>>(Wi1, Wr1, Wi2, Wr2, Wi3, Wr3, ws);

    p1_l1<<<1024, 512, 0, stream>>>(x, wcat1, xiA, rB, sum1, sqs1);
    p3_kernel<64, 16, 16, 2, 2, 0><<<1024, 256, 0, stream>>>(
        xiA, rB, sum1, sqs1, g1, be1, Wsp1, out1, 1.f / (1024.f * 64.f));

    p1_l2<<<1024, 256, 0, stream>>>(out1, wcat2, xiA, rB, sum2, sqs2);
    p3_kernel<128, 8, 8, 2, 2, 0><<<1024, 256, 0, stream>>>(
        xiA, rB, sum2, sqs2, g2, be2, Wsp2, out2, 1.f / (1024.f * 16.f));

    p1_l3<<<1024, 256, 0, stream>>>(out2, wcat3, xiA, rB, sum3, sqs3);
    p3_kernel<256, 4, 4, 3, 1, 1><<<1024, 256, 0, stream>>>(
        xiA, rB, sum3, sqs3, g3, be3, Wsp3, out3, 1.f / (1024.f * 16.f));

    fc_kernel<<<1024, 256, 0, stream>>>(out3, Wfc, bfc, out);
}